// Round 7
// baseline (538.430 us; speedup 1.0000x reference)
//
#include <hip/hip_runtime.h>

typedef _Float16 f16;
typedef __attribute__((ext_vector_type(8))) _Float16 f16x8;
typedef __attribute__((ext_vector_type(8))) short s16x8;
typedef __attribute__((ext_vector_type(4))) float f32x4;
typedef __attribute__((ext_vector_type(4))) unsigned short us16x4;

#define DIN   1024
#define DD    128
#define NBAT  4
#define TLEN  4096

// ---------- scalar conversions ----------
static __device__ __forceinline__ unsigned short f2bf(float f) {
  unsigned int u = __builtin_bit_cast(unsigned int, f);
  u = (u + 0x7fffu + ((u >> 16) & 1u)) >> 16;
  return (unsigned short)u;
}
static __device__ __forceinline__ float bf2f(unsigned short h) {
  return __builtin_bit_cast(float, (unsigned int)h << 16);
}
static __device__ __forceinline__ unsigned short f2h(float f) {
  _Float16 h = (_Float16)f;
  return __builtin_bit_cast(unsigned short, h);
}
// 64-elem row swizzle: 8 granules of 8 elems, key XOR
static __device__ __forceinline__ int swz64(int c, int key) {
  return ((((c >> 3) ^ key) & 7) << 3) | (c & 7);
}

// ---------- async global->LDS, width 16 ----------
typedef __attribute__((address_space(1))) const unsigned int* gas1_t;
typedef __attribute__((address_space(3))) unsigned int* las3_t;
static __device__ __forceinline__ void gload16(const void* g, void* l) {
  __builtin_amdgcn_global_load_lds((gas1_t)g, (las3_t)l, 16, 0, 0);
}

// =====================================================================
// Kernel 1: W' = bf16 hi/lo of [Wq|Wk|Wv]^T, [col 0..383][DIN],
// pre-swizzled in 64-elem chunks with key = col&7 (for gload_lds consumer).
// =====================================================================
__global__ void build_wt(const float* __restrict__ Wq, const float* __restrict__ Wk,
                         const float* __restrict__ Wv,
                         unsigned short* __restrict__ Wh, unsigned short* __restrict__ Wl) {
  int col = blockIdx.x;                 // 0..383
  const float* W = (col < 128) ? Wq : (col < 256 ? Wk : Wv);
  int j = col & 127;
  for (int kk = (int)threadIdx.x; kk < DIN; kk += blockDim.x) {
    float w = W[(size_t)kk * DD + j];
    unsigned short h = f2bf(w);
    unsigned short l = f2bf(w - bf2f(h));
    int c64 = kk >> 6, w64 = kk & 63;
    int kks = (c64 << 6) + swz64(w64, col & 7);
    Wh[(size_t)col * DIN + kks] = h;
    Wl[(size_t)col * DIN + kks] = l;
  }
}

// =====================================================================
// Kernel 2: projection GEMM (round-1 verified structure). 128x128 tile,
// BK=64, 4 waves (2x2, 64x64 each), bf16 hi/lo 3-product. x converted
// in-kernel to LDS; W' staged via gload_lds (pre-swizzled source).
// Outputs: q,k plain f16 [t][d]; v plain f16 [n][d][t] (LDS-alias transpose).
// =====================================================================
__global__ __launch_bounds__(256, 2) void proj_qkv(
    const float* __restrict__ x,
    const unsigned short* __restrict__ Wh, const unsigned short* __restrict__ Wl,
    unsigned short* __restrict__ qws, unsigned short* __restrict__ kws,
    unsigned short* __restrict__ vws) {
  __shared__ __align__(16) unsigned short U[4 * 128 * 64];  // Ah|Al|Bh|Bl, 64KB
  unsigned short* Ah = U;
  unsigned short* Al = U + 8192;
  unsigned short* Bh = U + 16384;
  unsigned short* Bl = U + 24576;

  const int tid = (int)threadIdx.x;
  const int lane = tid & 63;
  const int lg = lane >> 4;
  const int lr = lane & 15;
  const int wid = tid >> 6;
  const int t0 = blockIdx.x * 128;
  const int ct = blockIdx.y;            // 0=q 1=k 2=v

  const int rbase = (wid >> 1) * 64;
  const int cbase = (wid & 1) * 64;

  f32x4 acc[4][4];
#pragma unroll
  for (int m = 0; m < 4; ++m)
#pragma unroll
    for (int n = 0; n < 4; ++n) acc[m][n] = f32x4{0.f, 0.f, 0.f, 0.f};

  for (int kr = 0; kr < 16; ++kr) {
#pragma unroll
    for (int rr = 0; rr < 8; ++rr) {
      int idx = rr * 256 + tid;
      int row = idx >> 4;
      int c0 = (idx & 15) * 4;
      f32x4 xv = *(const f32x4*)(x + (size_t)(t0 + row) * DIN + kr * 64 + c0);
      int g = swz64(c0, row & 7);
      unsigned short hs0 = f2bf(xv[0]), hs1 = f2bf(xv[1]), hs2 = f2bf(xv[2]), hs3 = f2bf(xv[3]);
      us16x4 hv = {hs0, hs1, hs2, hs3};
      us16x4 lv = {f2bf(xv[0] - bf2f(hs0)), f2bf(xv[1] - bf2f(hs1)),
                   f2bf(xv[2] - bf2f(hs2)), f2bf(xv[3] - bf2f(hs3))};
      *(us16x4*)&Ah[row * 64 + g] = hv;
      *(us16x4*)&Al[row * 64 + g] = lv;
    }
#pragma unroll
    for (int rr = 0; rr < 4; ++rr) {
      int idx = rr * 256 + tid;
      int row = idx >> 3;
      int g = idx & 7;
      size_t gbyte = ((size_t)(ct * 128 + row) * DIN + (size_t)kr * 64) * 2 + (size_t)g * 16;
      gload16((const char*)Wh + gbyte, (char*)Bh + (size_t)idx * 16);
      gload16((const char*)Wl + gbyte, (char*)Bl + (size_t)idx * 16);
    }
    __syncthreads();

#pragma unroll
    for (int kc = 0; kc < 2; ++kc) {
      s16x8 ah[4], al[4], bh[4], bl[4];
#pragma unroll
      for (int m = 0; m < 4; ++m) {
        int r = rbase + m * 16 + lr;
        int g = ((kc * 4 + lg) ^ (r & 7)) * 8;
        ah[m] = *(const s16x8*)&Ah[r * 64 + g];
        al[m] = *(const s16x8*)&Al[r * 64 + g];
      }
#pragma unroll
      for (int n = 0; n < 4; ++n) {
        int c = cbase + n * 16 + lr;
        int g = ((kc * 4 + lg) ^ (c & 7)) * 8;
        bh[n] = *(const s16x8*)&Bh[c * 64 + g];
        bl[n] = *(const s16x8*)&Bl[c * 64 + g];
      }
#pragma unroll
      for (int m = 0; m < 4; ++m)
#pragma unroll
        for (int n = 0; n < 4; ++n) {
          acc[m][n] = __builtin_amdgcn_mfma_f32_16x16x32_bf16(ah[m], bh[n], acc[m][n], 0, 0, 0);
          acc[m][n] = __builtin_amdgcn_mfma_f32_16x16x32_bf16(ah[m], bl[n], acc[m][n], 0, 0, 0);
          acc[m][n] = __builtin_amdgcn_mfma_f32_16x16x32_bf16(al[m], bh[n], acc[m][n], 0, 0, 0);
        }
    }
    __syncthreads();
  }

  const int n = t0 >> 12, t0l = t0 & (TLEN - 1);
  if (ct < 2) {
    unsigned short* dstb = (ct == 0) ? qws : kws;
#pragma unroll
    for (int m = 0; m < 4; ++m)
#pragma unroll
      for (int nn = 0; nn < 4; ++nn)
#pragma unroll
        for (int e = 0; e < 4; ++e) {
          int t = t0 + rbase + m * 16 + lg * 4 + e;
          int d = cbase + nn * 16 + lr;
          dstb[(size_t)t * DD + d] = f2h(acc[m][nn][e]);
        }
  } else {
    // v: C-frags -> LDS transpose buffer vt[d][tl] (stride 132), then coalesced store
    unsigned short* vt = U;             // alias (staging done)
#pragma unroll
    for (int m = 0; m < 4; ++m)
#pragma unroll
      for (int nn = 0; nn < 4; ++nn)
#pragma unroll
        for (int e = 0; e < 4; ++e) {
          int tl = rbase + m * 16 + lg * 4 + e;   // 0..127
          int d = cbase + nn * 16 + lr;
          vt[d * 132 + tl] = f2h(acc[m][nn][e]);
        }
    __syncthreads();
    int d = tid >> 1;                   // 0..127
    int half = (tid & 1) * 64;
    unsigned short* dst = vws + ((size_t)n * DD + d) * TLEN + t0l + half;
#pragma unroll
    for (int h = 0; h < 8; ++h) {
      *(f16x8*)(dst + h * 8) = *(const f16x8*)&vt[d * 132 + half + h * 8];
    }
  }
}

// =====================================================================
// Kernel 3: attn_z — causal row-sums Z (barrier-free j-loop, direct-global
// k fragments) + this block's upper-triangle zero-fill. Writes rz scratch.
// 512 blocks x 512 thr, 32-row q-tiles, cr-balanced mapping.
// =====================================================================
__global__ __launch_bounds__(512, 4) void attn_z(
    const unsigned short* __restrict__ qws, const unsigned short* __restrict__ kws,
    float* __restrict__ rzg, float* __restrict__ att) {
  __shared__ float zb[8][16];

  const int tid = (int)threadIdx.x;
  const int lane = tid & 63;
  const int wid = tid >> 6;
  const int lr = lane & 15;
  const int lg = lane >> 4;
  const int rg = wid >> 2;
  const int cg = wid & 3;

  int b = (int)blockIdx.x;
  int cr = (b < 256) ? b : (767 - b);
  const int qi = cr >> 2;
  const int n = cr & 3;
  const int t0 = qi * 32;
  const int jmax = t0 >> 7;

  const unsigned short* kbase = kws + (size_t)(n * TLEN) * DD;
  float* attn_base = att + (size_t)n * TLEN * TLEN + (size_t)t0 * TLEN;

  // ---- zero-fill upper region (stores retire during compute) ----
  {
    int cz0 = (jmax + 1) * 128;
    f32x4 zv = f32x4{0.f, 0.f, 0.f, 0.f};
    for (int r = 0; r < 32; ++r) {
      float* rowp = attn_base + (size_t)r * TLEN;
      for (int c = cz0 + tid * 4; c < TLEN; c += 2048) *(f32x4*)(rowp + c) = zv;
    }
  }

  f16x8 qa[4];
  {
    const unsigned short* q0 = qws + (size_t)(n * TLEN + t0 + rg * 16 + lr) * DD + lg * 8;
#pragma unroll
    for (int kc = 0; kc < 4; ++kc) qa[kc] = *(const f16x8*)(q0 + kc * 32);
  }
  const int rowl0 = rg * 16 + lg * 4;

  float zacc[4] = {0.f, 0.f, 0.f, 0.f};
  for (int j = 0; j <= jmax; ++j) {
#pragma unroll
    for (int cf = 0; cf < 2; ++cf) {
      int krow = cg * 32 + cf * 16 + lr;
      const unsigned short* kt = kbase + (size_t)(j * 128 + krow) * DD + lg * 8;
      f32x4 s = f32x4{0.f, 0.f, 0.f, 0.f};
#pragma unroll
      for (int kc = 0; kc < 4; ++kc) {
        f16x8 kb = *(const f16x8*)(kt + kc * 32);
        s = __builtin_amdgcn_mfma_f32_16x16x32_f16(qa[kc], kb, s, 0, 0, 0);
      }
      int colg = j * 128 + krow;
#pragma unroll
      for (int e = 0; e < 4; ++e) {
        int rowg = t0 + rowl0 + e;
        zacc[e] += (colg <= rowg && s[e] != 0.0f) ? __expf(s[e]) : 0.0f;
      }
    }
  }
#pragma unroll
  for (int e = 0; e < 4; ++e) {
    float z = zacc[e];
    z += __shfl_xor(z, 1);
    z += __shfl_xor(z, 2);
    z += __shfl_xor(z, 4);
    z += __shfl_xor(z, 8);
    if (lr == 0) zb[wid][lg * 4 + e] = z;
  }
  __syncthreads();
  if (tid < 32) {
    int rgq = tid >> 4, rl = tid & 15;
    float z = zb[rgq * 4 + 0][rl] + zb[rgq * 4 + 1][rl] + zb[rgq * 4 + 2][rl] + zb[rgq * 4 + 3][rl];
    rzg[(size_t)n * TLEN + t0 + tid] = (z > 0.f) ? (1.0f / z) : 0.0f;
  }
}

// =====================================================================
// Kernel 4: attn_pv — recompute s bitwise-identically, write normalized
// att (vectorized via wave-private LDS bounce), PV-accumulate, out.
// NO barriers in the j-loop: k,v direct from global (64B-coalesced, L2-
// resident), p-bounce wave-private (lgkmcnt only). Epilogue: LDS reduce.
// =====================================================================
__global__ __launch_bounds__(512, 4) void attn_pv(
    const unsigned short* __restrict__ qws, const unsigned short* __restrict__ kws,
    const unsigned short* __restrict__ vws, const float* __restrict__ rzg,
    float* __restrict__ out, float* __restrict__ att) {
  __shared__ __align__(16) char smem[65536];  // ppw (10KB) then red (64KB) alias

  const int tid = (int)threadIdx.x;
  const int lane = tid & 63;
  const int wid = tid >> 6;
  const int lr = lane & 15;
  const int lg = lane >> 4;
  const int rg = wid >> 2;
  const int cg = wid & 3;

  int b = (int)blockIdx.x;
  int cr = (b < 256) ? b : (767 - b);
  const int qi = cr >> 2;
  const int n = cr & 3;
  const int t0 = qi * 32;
  const int jmax = t0 >> 7;

  const unsigned short* kbase = kws + (size_t)(n * TLEN) * DD;
  const unsigned short* vbase = vws + (size_t)n * DD * TLEN;
  float* attn_base = att + (size_t)n * TLEN * TLEN + (size_t)t0 * TLEN;

  f16x8 qa[4];
  {
    const unsigned short* q0 = qws + (size_t)(n * TLEN + t0 + rg * 16 + lr) * DD + lg * 8;
#pragma unroll
    for (int kc = 0; kc < 4; ++kc) qa[kc] = *(const f16x8*)(q0 + kc * 32);
  }
  const int rowl0 = rg * 16 + lg * 4;
  float rz[4];
#pragma unroll
  for (int e = 0; e < 4; ++e) rz[e] = rzg[(size_t)n * TLEN + t0 + rowl0 + e];

  unsigned short* ppw = (unsigned short*)(smem + wid * 1280);  // [16 rows][40]

  f32x4 oacc[8];
#pragma unroll
  for (int fd = 0; fd < 8; ++fd) oacc[fd] = f32x4{0.f, 0.f, 0.f, 0.f};

  for (int j = 0; j <= jmax; ++j) {
    // QK (bitwise identical to attn_z)
    f32x4 s[2];
#pragma unroll
    for (int cf = 0; cf < 2; ++cf) {
      int krow = cg * 32 + cf * 16 + lr;
      const unsigned short* kt = kbase + (size_t)(j * 128 + krow) * DD + lg * 8;
      s[cf] = f32x4{0.f, 0.f, 0.f, 0.f};
#pragma unroll
      for (int kc = 0; kc < 4; ++kc) {
        f16x8 kb = *(const f16x8*)(kt + kc * 32);
        s[cf] = __builtin_amdgcn_mfma_f32_16x16x32_f16(qa[kc], kb, s[cf], 0, 0, 0);
      }
    }
    // v fragments (issued early, consumed by PV)
    f16x8 vb[8];
#pragma unroll
    for (int fd = 0; fd < 8; ++fd) {
      vb[fd] = *(const f16x8*)(vbase + (size_t)(fd * 16 + lr) * TLEN + (size_t)j * 128 + cg * 32 + lg * 8);
    }
    // exp + normalized p into wave-private LDS
#pragma unroll
    for (int cf = 0; cf < 2; ++cf) {
      int krow = cg * 32 + cf * 16 + lr;
      int colg = j * 128 + krow;
#pragma unroll
      for (int e = 0; e < 4; ++e) {
        int rowg = t0 + rowl0 + e;
        float ev = (colg <= rowg && s[cf][e] != 0.0f) ? __expf(s[cf][e]) : 0.0f;
        ppw[(lg * 4 + e) * 40 + cf * 16 + lr] = f2h(ev * rz[e]);
      }
    }
    // PV A-frag (wave-synchronous LDS read, no barrier)
    f16x8 pa = *(const f16x8*)&ppw[lr * 40 + lg * 8];
#pragma unroll
    for (int fd = 0; fd < 8; ++fd) {
      oacc[fd] = __builtin_amdgcn_mfma_f32_16x16x32_f16(pa, vb[fd], oacc[fd], 0, 0, 0);
    }
    // vectorized att store: lane -> row lane>>2, 8 cols at (lane&3)*8
    {
      int r = lane >> 2, cs = (lane & 3) * 8;
      f16x8 pv = *(const f16x8*)&ppw[r * 40 + cs];
      f32x4 o0, o1;
#pragma unroll
      for (int i = 0; i < 4; ++i) { o0[i] = (float)pv[i]; o1[i] = (float)pv[4 + i]; }
      float* dst = attn_base + (size_t)(rg * 16 + r) * TLEN + j * 128 + cg * 32 + cs;
      *(f32x4*)dst = o0;
      *(f32x4*)(dst + 4) = o1;
    }
  }

  // ---- cross-wave PV reduction ----
  __syncthreads();
  float* red = (float*)smem;            // [8][16][128]
#pragma unroll
  for (int fd = 0; fd < 8; ++fd)
#pragma unroll
    for (int e = 0; e < 4; ++e)
      red[((size_t)wid * 16 + lg * 4 + e) * 128 + fd * 16 + lr] = oacc[fd][e];
  __syncthreads();
  {
    int r = tid >> 4;                   // 0..31
    int d0 = (tid & 15) * 8;
    int rgq = r >> 4, rl = r & 15;
    f32x4 s0 = f32x4{0.f, 0.f, 0.f, 0.f}, s1 = f32x4{0.f, 0.f, 0.f, 0.f};
#pragma unroll
    for (int c = 0; c < 4; ++c) {
      const float* src = red + ((size_t)(rgq * 4 + c) * 16 + rl) * 128 + d0;
      f32x4 a = *(const f32x4*)src;
      f32x4 bb = *(const f32x4*)(src + 4);
#pragma unroll
      for (int i = 0; i < 4; ++i) { s0[i] += a[i]; s1[i] += bb[i]; }
    }
    float* dst = out + ((size_t)n * TLEN + t0 + r) * DD + d0;
    *(f32x4*)dst = s0;
    *(f32x4*)(dst + 4) = s1;
  }
}

// =====================================================================
extern "C" void kernel_launch(void* const* d_in, const int* in_sizes, int n_in,
                              void* d_out, int out_size, void* d_ws, size_t ws_size,
                              hipStream_t stream) {
  const float* x  = (const float*)d_in[0];
  const float* Wq = (const float*)d_in[1];
  const float* Wk = (const float*)d_in[2];
  const float* Wv = (const float*)d_in[3];

  float* out = (float*)d_out;                              // [4,4096,128]
  float* att = out + (size_t)NBAT * TLEN * DD;             // [4,4096,4096]

  unsigned short* ws = (unsigned short*)d_ws;
  unsigned short* Wh  = ws;                                // 384*1024 (swizzled chunks)
  unsigned short* Wl  = Wh + (size_t)384 * DIN;
  unsigned short* qws = Wl + (size_t)384 * DIN;            // [t][d] plain f16
  unsigned short* kws = qws + (size_t)NBAT * TLEN * DD;    // [t][d] plain f16
  unsigned short* vws = kws + (size_t)NBAT * TLEN * DD;    // [n][d][t] plain f16
  float* rzg = (float*)(vws + (size_t)NBAT * TLEN * DD);   // [4][4096] f32

  build_wt<<<dim3(384), dim3(256), 0, stream>>>(Wq, Wk, Wv, Wh, Wl);
  proj_qkv<<<dim3(128, 3), dim3(256), 0, stream>>>(x, Wh, Wl, qws, kws, vws);
  attn_z<<<dim3(512), dim3(512), 0, stream>>>(qws, kws, rzg, att);
  attn_pv<<<dim3(512), dim3(512), 0, stream>>>(qws, kws, vws, rzg, out, att);
}